// Round 1
// baseline (2474.190 us; speedup 1.0000x reference)
//
#include <hip/hip_runtime.h>
#include <cstdint>
#include <cstddef>

#define EPISODES 128
#define LPAD     512
#define DDIM     512
#define CG_ITERS 48
#define CHUNK    24

__device__ __forceinline__ int lower_bound_dev(const int* __restrict__ a, int n, int key){
    int lo = 0, hi = n;
    while(lo < hi){
        int m = (lo + hi) >> 1;
        if(a[m] < key) lo = m + 1; else hi = m;
    }
    return lo;
}

// ---------------------------------------------------------------------------
// Kernel 1: per-episode segmentation, rank assignment (order-preserving),
// gather of support/query indices + labels, counts, and the three means.
// One workgroup (256 threads) per episode. batch_index is sorted, so each
// episode is a contiguous segment; ranks via ballot prefix-scan.
// ---------------------------------------------------------------------------
__global__ __launch_bounds__(256) void k_gather(
        const int* __restrict__ labels, const int* __restrict__ is_query,
        const int* __restrict__ bidx, const float* __restrict__ X, int N,
        int* __restrict__ sup_idx, int* __restrict__ qry_idx,
        int* __restrict__ sup_lab, int* __restrict__ counts,
        float* __restrict__ task_mean, float* __restrict__ pos_mean,
        float* __restrict__ neg_mean)
{
    const int b    = blockIdx.x;
    const int tid  = threadIdx.x;
    const int lane = tid & 63;
    const int wave = tid >> 6;

    __shared__ int s_start, s_end;
    __shared__ int wq[4];
    __shared__ int s_runq, s_npos;

    if(tid == 0){
        s_start = lower_bound_dev(bidx, N, b);
        s_end   = lower_bound_dev(bidx, N, b + 1);
        s_runq  = 0;
        s_npos  = 0;
    }
    __syncthreads();
    const int start = s_start, end = s_end;

    for(int base = start; base < end; base += 256){
        int idx   = base + tid;
        bool valid = idx < end;
        int q   = valid ? is_query[idx] : 0;
        int lab = valid ? labels[idx]   : 0;
        unsigned long long m = __ballot(q == 1);
        if(lane == 0) wq[wave] = __popcll(m);
        __syncthreads();
        int woff = 0;
        for(int w = 0; w < wave; w++) woff += wq[w];
        int qbefore = __popcll(m & ((1ull << lane) - 1ull)) + woff;
        int runq0 = s_runq;
        int chunk_total = wq[0] + wq[1] + wq[2] + wq[3];
        if(valid){
            int pos_in_seg = idx - start;
            if(q){
                int qr = runq0 + qbefore;
                if(qr < LPAD) qry_idx[b * LPAD + qr] = idx;
            } else {
                int sr = pos_in_seg - runq0 - qbefore;
                if(sr < LPAD){
                    sup_idx[b * LPAD + sr] = idx;
                    sup_lab[b * LPAD + sr] = lab;
                    if(lab == 1) atomicAdd(&s_npos, 1);
                }
            }
        }
        __syncthreads();
        if(tid == 0) s_runq = runq0 + chunk_total;
        __syncthreads();
    }

    const int nq   = s_runq;
    const int ns   = (end - start) - nq;
    const int npos = s_npos;
    const int nneg = ns - npos;
    if(tid == 0){
        counts[b*4 + 0] = ns;
        counts[b*4 + 1] = nq;
        counts[b*4 + 2] = npos;
        counts[b*4 + 3] = nneg;
    }
    __syncthreads();

    // Means: thread owns dims d0 = tid and d1 = tid + 256.
    const int d0 = tid, d1 = tid + 256;
    float sa0 = 0.f, sa1 = 0.f, sp0 = 0.f, sp1 = 0.f, sn0 = 0.f, sn1 = 0.f;
    for(int s = 0; s < ns; s++){
        int n   = sup_idx[b * LPAD + s];
        int lab = sup_lab[b * LPAD + s];
        float x0 = X[(size_t)n * DDIM + d0];
        float x1 = X[(size_t)n * DDIM + d1];
        sa0 += x0; sa1 += x1;
        if(lab){ sp0 += x0; sp1 += x1; } else { sn0 += x0; sn1 += x1; }
    }
    float fns = (float)ns, fnp = (float)npos, fnn = (float)nneg;
    task_mean[b*DDIM + d0] = sa0 / fns;  task_mean[b*DDIM + d1] = sa1 / fns;
    pos_mean [b*DDIM + d0] = sp0 / fnp;  pos_mean [b*DDIM + d1] = sp1 / fnp;
    neg_mean [b*DDIM + d0] = sn0 / fnn;  neg_mean [b*DDIM + d1] = sn1 / fnn;
}

// ---------------------------------------------------------------------------
// Kernel 2: CG solve of M v = 1 for each (episode, class) system.
// M = 0.9*task_cov + 0.1*cls_cov + 0.1*I, applied matrix-free in sample space.
// One workgroup of 512 threads per system; thread t owns dimension t.
// ---------------------------------------------------------------------------
__global__ __launch_bounds__(512) void k_cg(
        const float* __restrict__ X,
        const int* __restrict__ sup_idx, const int* __restrict__ sup_lab,
        const int* __restrict__ counts,
        const float* __restrict__ task_mean, const float* __restrict__ pos_mean,
        const float* __restrict__ neg_mean,
        float* __restrict__ vout)
{
    const int sys  = blockIdx.x;
    const int b    = sys >> 1;
    const int cls  = sys & 1;          // 0 = negative-class system, 1 = positive
    const int tid  = threadIdx.x;
    const int lane = tid & 63;
    const int wave = tid >> 6;
    const int d    = tid;

    __shared__ float xs[CHUNK][DDIM];      // 48 KB row chunk
    __shared__ float p_lds[DDIM];
    __shared__ float w_lds[CHUNK];
    __shared__ int   lab_lds[CHUNK];
    __shared__ int   idx_lds[CHUNK];
    __shared__ float red1[8];
    __shared__ float red2[8][2];

    const int ns   = counts[b*4 + 0];
    const int ncls = cls ? counts[b*4 + 2] : counts[b*4 + 3];
    const float c_task = 0.9f / (float)(ns - 1);
    const float c_cls  = 0.1f / (float)(ncls - 1);

    const float mu_d    = task_mean[b*DDIM + d];
    const float mucls_d = cls ? pos_mean[b*DDIM + d] : neg_mean[b*DDIM + d];

    auto blockReduce = [&](float v) -> float {
        #pragma unroll
        for(int off = 32; off; off >>= 1) v += __shfl_xor(v, off);
        __syncthreads();                       // protect red1 reuse
        if(lane == 0) red1[wave] = v;
        __syncthreads();
        float s = 0.f;
        #pragma unroll
        for(int w = 0; w < 8; w++) s += red1[w];
        return s;                              // identical on every thread
    };

    // q = M p.  Requires p_lds valid + synced; pd_reg = p[d].
    auto matvec = [&](float pd_reg) -> float {
        // a0 = mu . p ; a1 = mu_cls . p  (two fused block reductions)
        float part0 = mu_d * pd_reg, part1 = mucls_d * pd_reg;
        #pragma unroll
        for(int off = 32; off; off >>= 1){
            part0 += __shfl_xor(part0, off);
            part1 += __shfl_xor(part1, off);
        }
        __syncthreads();
        if(lane == 0){ red2[wave][0] = part0; red2[wave][1] = part1; }
        __syncthreads();
        float a0 = 0.f, a1 = 0.f;
        #pragma unroll
        for(int w = 0; w < 8; w++){ a0 += red2[w][0]; a1 += red2[w][1]; }

        // per-lane register copy of p (stride-64 layout, conflict-free)
        float preg[8];
        #pragma unroll
        for(int k = 0; k < 8; k++) preg[k] = p_lds[lane + 64*k];

        float q = 0.1f * pd_reg;
        for(int cs = 0; cs < ns; cs += CHUNK){
            int nrows = min(CHUNK, ns - cs);
            __syncthreads();                   // xs free from previous pass2
            if(tid < nrows){
                idx_lds[tid] = sup_idx[b * LPAD + cs + tid];
                lab_lds[tid] = sup_lab[b * LPAD + cs + tid];
            }
            __syncthreads();
            // stage rows into LDS (coalesced float4)
            for(int f = tid; f < nrows * 128; f += 512){
                int r  = f >> 7;
                int c4 = f & 127;
                const float4* src = (const float4*)(X + (size_t)idx_lds[r] * DDIM);
                ((float4*)&xs[r][0])[c4] = src[c4];
            }
            __syncthreads();
            // pass 1: per-row dots t = x_s . p, coefficient w_s
            for(int r = wave; r < nrows; r += 8){
                float t = 0.f;
                #pragma unroll
                for(int k = 0; k < 8; k++) t += xs[r][lane + 64*k] * preg[k];
                #pragma unroll
                for(int off = 32; off; off >>= 1) t += __shfl_xor(t, off);
                if(lane == 0){
                    int lm = (lab_lds[r] == cls) ? 1 : 0;
                    w_lds[r] = c_task * (t - a0) + (lm ? c_cls * (t - a1) : 0.f);
                }
            }
            __syncthreads();
            // pass 2: q[d] += sum_s w_s * x_s[d]  (conflict-free b32 reads)
            for(int r = 0; r < nrows; r++) q += w_lds[r] * xs[r][d];
        }
        return q;
    };

    // x0 = 10 * ones: exact on the 0.1-eigenvalue null space of the low-rank
    // part, so CG only works in range(centered support) (kappa_eff ~ 16).
    float xv = 10.0f;
    float pd = 10.0f;
    p_lds[d] = pd;
    __syncthreads();
    float qd = matvec(pd);
    float rd = 1.0f - qd;
    pd = rd;
    float rr = blockReduce(rd * rd);
    __syncthreads();
    p_lds[d] = pd;
    __syncthreads();

    for(int it = 0; it < CG_ITERS; it++){
        if(rr < 1e-30f) break;                 // uniform across block
        qd = matvec(pd);
        float pq = blockReduce(pd * qd);
        float alpha = rr / pq;
        xv += alpha * pd;
        rd -= alpha * qd;
        float rr_new = blockReduce(rd * rd);
        float beta = rr_new / rr;
        rr = rr_new;
        pd = rd + beta * pd;
        __syncthreads();
        p_lds[d] = pd;
        __syncthreads();
    }

    vout[(size_t)(b*2 + cls) * DDIM + d] = xv;
}

// ---------------------------------------------------------------------------
// Kernel 3: per-query output.
// maha_c = (x.v_c - mean_c.v_c) * (sum(x) - sum(mean_c)); out = [neg,pos]*scale
// One workgroup (256 threads = 4 waves) per episode; one wave per query row.
// ---------------------------------------------------------------------------
__global__ __launch_bounds__(256) void k_out(
        const float* __restrict__ X,
        const int* __restrict__ qry_idx, const int* __restrict__ counts,
        const float* __restrict__ pos_mean, const float* __restrict__ neg_mean,
        const float* __restrict__ vsol, const float* __restrict__ log_scale,
        float* __restrict__ out)
{
    const int b    = blockIdx.x;
    const int tid  = threadIdx.x;
    const int lane = tid & 63;
    const int wave = tid >> 6;

    __shared__ float vpos[DDIM], vneg[DDIM];
    __shared__ float red4[4][4];
    __shared__ float sc[4];                    // smp, smn, mvp, mvn

    const int nq  = counts[b*4 + 1];
    const int nqc = min(nq, LPAD);
    const float scale = expf(log_scale[0]);

    float pm0 = pos_mean[b*DDIM + tid], pm1 = pos_mean[b*DDIM + tid + 256];
    float nm0 = neg_mean[b*DDIM + tid], nm1 = neg_mean[b*DDIM + tid + 256];
    float vp0 = vsol[(size_t)(b*2 + 1) * DDIM + tid];
    float vp1 = vsol[(size_t)(b*2 + 1) * DDIM + tid + 256];
    float vn0 = vsol[(size_t)(b*2 + 0) * DDIM + tid];
    float vn1 = vsol[(size_t)(b*2 + 0) * DDIM + tid + 256];
    vpos[tid] = vp0; vpos[tid + 256] = vp1;
    vneg[tid] = vn0; vneg[tid + 256] = vn1;

    float smp = pm0 + pm1;
    float smn = nm0 + nm1;
    float mvp = pm0 * vp0 + pm1 * vp1;
    float mvn = nm0 * vn0 + nm1 * vn1;
    #pragma unroll
    for(int off = 32; off; off >>= 1){
        smp += __shfl_xor(smp, off);
        smn += __shfl_xor(smn, off);
        mvp += __shfl_xor(mvp, off);
        mvn += __shfl_xor(mvn, off);
    }
    if(lane == 0){
        red4[wave][0] = smp; red4[wave][1] = smn;
        red4[wave][2] = mvp; red4[wave][3] = mvn;
    }
    __syncthreads();
    if(tid < 4) sc[tid] = red4[0][tid] + red4[1][tid] + red4[2][tid] + red4[3][tid];
    __syncthreads();

    for(int r = wave; r < nqc; r += 4){
        int n = qry_idx[b * LPAD + r];
        float tp = 0.f, tn = 0.f, sx = 0.f;
        #pragma unroll
        for(int k = 0; k < 8; k++){
            float x = X[(size_t)n * DDIM + lane + 64*k];
            tp += x * vpos[lane + 64*k];
            tn += x * vneg[lane + 64*k];
            sx += x;
        }
        #pragma unroll
        for(int off = 32; off; off >>= 1){
            tp += __shfl_xor(tp, off);
            tn += __shfl_xor(tn, off);
            sx += __shfl_xor(sx, off);
        }
        if(lane == 0){
            float mp = (tp - sc[2]) * (sx - sc[0]);
            float mn = (tn - sc[3]) * (sx - sc[1]);
            ((float2*)out)[(size_t)b * LPAD + r] = make_float2(mn * scale, mp * scale);
        }
    }
    // masked query rows -> exact zeros (d_out is poisoned before each launch)
    for(int r = nqc + tid; r < LPAD; r += 256)
        ((float2*)out)[(size_t)b * LPAD + r] = make_float2(0.f, 0.f);
}

// ---------------------------------------------------------------------------
extern "C" void kernel_launch(void* const* d_in, const int* in_sizes, int n_in,
                              void* d_out, int out_size, void* d_ws, size_t ws_size,
                              hipStream_t stream)
{
    const float* X         = (const float*)d_in[0];
    const float* log_scale = (const float*)d_in[1];
    const int*   labels    = (const int*)d_in[2];
    const int*   is_query  = (const int*)d_in[3];
    const int*   bidx      = (const int*)d_in[4];
    const int N = in_sizes[2];                 // flat sample count

    char* ws = (char*)d_ws;
    int* sup_idx = (int*)ws;              ws += EPISODES * LPAD * sizeof(int);
    int* qry_idx = (int*)ws;              ws += EPISODES * LPAD * sizeof(int);
    int* sup_lab = (int*)ws;              ws += EPISODES * LPAD * sizeof(int);
    int* counts  = (int*)ws;              ws += EPISODES * 4 * sizeof(int);
    float* task_mean = (float*)ws;        ws += EPISODES * DDIM * sizeof(float);
    float* pos_mean  = (float*)ws;        ws += EPISODES * DDIM * sizeof(float);
    float* neg_mean  = (float*)ws;        ws += EPISODES * DDIM * sizeof(float);
    float* vsol      = (float*)ws;        ws += EPISODES * 2 * DDIM * sizeof(float);

    k_gather<<<EPISODES, 256, 0, stream>>>(labels, is_query, bidx, X, N,
                                           sup_idx, qry_idx, sup_lab, counts,
                                           task_mean, pos_mean, neg_mean);
    k_cg<<<EPISODES * 2, 512, 0, stream>>>(X, sup_idx, sup_lab, counts,
                                           task_mean, pos_mean, neg_mean, vsol);
    k_out<<<EPISODES, 256, 0, stream>>>(X, qry_idx, counts, pos_mean, neg_mean,
                                        vsol, log_scale, (float*)d_out);
}

// Round 2
// 866.998 us; speedup vs baseline: 2.8537x; 2.8537x over previous
//
#include <hip/hip_runtime.h>
#include <cstdint>
#include <cstddef>

#define EPISODES 128
#define LPAD     512
#define DDIM     512
#define NS_CAP   320
#define GTILE    64
#define NPAIRS   15          // 5*(5+1)/2 tile pairs (NS_CAP/GTILE = 5)
#define CG_ITERS 28
#define CHUNK    24          // fallback kernel
#define CG_ITERS_FB 48

__device__ __forceinline__ int lower_bound_dev(const int* __restrict__ a, int n, int key){
    int lo = 0, hi = n;
    while(lo < hi){
        int m = (lo + hi) >> 1;
        if(a[m] < key) lo = m + 1; else hi = m;
    }
    return lo;
}

// ---------------------------------------------------------------------------
// Kernel 1: per-episode segmentation, gather, counts, means, support row sums.
// ---------------------------------------------------------------------------
__global__ __launch_bounds__(256) void k_gather(
        const int* __restrict__ labels, const int* __restrict__ is_query,
        const int* __restrict__ bidx, const float* __restrict__ X, int N,
        int* __restrict__ sup_idx, int* __restrict__ qry_idx,
        int* __restrict__ sup_lab, int* __restrict__ counts,
        float* __restrict__ task_mean, float* __restrict__ pos_mean,
        float* __restrict__ neg_mean, float* __restrict__ row_sums)
{
    const int b    = blockIdx.x;
    const int tid  = threadIdx.x;
    const int lane = tid & 63;
    const int wave = tid >> 6;

    __shared__ int s_start, s_end;
    __shared__ int wq[4];
    __shared__ int s_runq, s_npos;

    if(tid == 0){
        s_start = lower_bound_dev(bidx, N, b);
        s_end   = lower_bound_dev(bidx, N, b + 1);
        s_runq  = 0;
        s_npos  = 0;
    }
    __syncthreads();
    const int start = s_start, end = s_end;

    for(int base = start; base < end; base += 256){
        int idx   = base + tid;
        bool valid = idx < end;
        int q   = valid ? is_query[idx] : 0;
        int lab = valid ? labels[idx]   : 0;
        unsigned long long m = __ballot(q == 1);
        if(lane == 0) wq[wave] = __popcll(m);
        __syncthreads();
        int woff = 0;
        for(int w = 0; w < wave; w++) woff += wq[w];
        int qbefore = __popcll(m & ((1ull << lane) - 1ull)) + woff;
        int runq0 = s_runq;
        int chunk_total = wq[0] + wq[1] + wq[2] + wq[3];
        if(valid){
            int pos_in_seg = idx - start;
            if(q){
                int qr = runq0 + qbefore;
                if(qr < LPAD) qry_idx[b * LPAD + qr] = idx;
            } else {
                int sr = pos_in_seg - runq0 - qbefore;
                if(sr < LPAD){
                    sup_idx[b * LPAD + sr] = idx;
                    sup_lab[b * LPAD + sr] = lab;
                    if(lab == 1) atomicAdd(&s_npos, 1);
                }
            }
        }
        __syncthreads();
        if(tid == 0) s_runq = runq0 + chunk_total;
        __syncthreads();
    }

    const int nq   = s_runq;
    const int ns   = (end - start) - nq;
    const int npos = s_npos;
    const int nneg = ns - npos;
    if(tid == 0){
        counts[b*4 + 0] = ns;
        counts[b*4 + 1] = nq;
        counts[b*4 + 2] = npos;
        counts[b*4 + 3] = nneg;
    }
    __syncthreads();

    // Means: thread owns dims d0 = tid and d1 = tid + 256.
    const int d0 = tid, d1 = tid + 256;
    float sa0 = 0.f, sa1 = 0.f, sp0 = 0.f, sp1 = 0.f, sn0 = 0.f, sn1 = 0.f;
    for(int s = 0; s < ns; s++){
        int n   = sup_idx[b * LPAD + s];
        int lab = sup_lab[b * LPAD + s];
        float x0 = X[(size_t)n * DDIM + d0];
        float x1 = X[(size_t)n * DDIM + d1];
        sa0 += x0; sa1 += x1;
        if(lab){ sp0 += x0; sp1 += x1; } else { sn0 += x0; sn1 += x1; }
    }
    float fns = (float)ns, fnp = (float)npos, fnn = (float)nneg;
    task_mean[b*DDIM + d0] = sa0 / fns;  task_mean[b*DDIM + d1] = sa1 / fns;
    pos_mean [b*DDIM + d0] = sp0 / fnp;  pos_mean [b*DDIM + d1] = sp1 / fnp;
    neg_mean [b*DDIM + d0] = sn0 / fnn;  neg_mean [b*DDIM + d1] = sn1 / fnn;

    // Support row sums (t_s for p = 1_D): one wave per row, lanes over dims.
    for(int r = wave; r < ns; r += 4){
        int n = sup_idx[b * LPAD + r];
        float s = 0.f;
        #pragma unroll
        for(int k = 0; k < 8; k++) s += X[(size_t)n * DDIM + lane + 64*k];
        #pragma unroll
        for(int off = 32; off; off >>= 1) s += __shfl_xor(s, off);
        if(lane == 0) row_sums[b * LPAD + r] = s;
    }
}

// ---------------------------------------------------------------------------
// Kernel 2: raw support Gram G0[b] = Xs Xs^T, zero-padded to NS_CAP x NS_CAP.
// 64x64 tiles (lower triangle + mirrored), 256 threads, 4x4 microtile,
// K-transposed LDS staging (stride 68 => 16B-aligned rows, ds_read_b128).
// ---------------------------------------------------------------------------
__global__ __launch_bounds__(256) void k_gram(
        const float* __restrict__ X, const int* __restrict__ sup_idx,
        const int* __restrict__ counts, float* __restrict__ G0)
{
    const int bid = blockIdx.x;
    const int b   = bid / NPAIRS;
    int tp = bid % NPAIRS;
    int ti = 0;
    while((ti+1)*(ti+2)/2 <= tp) ti++;
    const int tj  = tp - ti*(ti+1)/2;          // ti >= tj
    const int tid = threadIdx.x;
    const int ty  = tid >> 4, tx = tid & 15;

    const int ns  = counts[b*4 + 0];
    const int nsc = min(ns, NS_CAP);
    float* G = G0 + (size_t)b * NS_CAP * NS_CAP;

    // fast path: tile entirely in the zero-padding region
    if(ti * GTILE >= nsc){
        float4 z = make_float4(0.f, 0.f, 0.f, 0.f);
        #pragma unroll
        for(int t = 0; t < 4; t++){
            int f = tid + t*256; int rr = f >> 4; int c4 = f & 15;
            *(float4*)&G[(size_t)(ti*GTILE + rr)*NS_CAP + tj*GTILE + 4*c4] = z;
            if(ti != tj)
                *(float4*)&G[(size_t)(tj*GTILE + rr)*NS_CAP + ti*GTILE + 4*c4] = z;
        }
        return;
    }

    __shared__ float Sb[64*68];                // Ast[32][68]+Bst[32][68]; reused as Tl[64][68]
    __shared__ int ia[GTILE], ib[GTILE];
    float* Ast = Sb;
    float* Bst = Sb + 32*68;

    if(tid < GTILE)            ia[tid]      = sup_idx[b*LPAD + min(ti*GTILE + tid,        nsc-1)];
    else if(tid < 2*GTILE)     ib[tid - 64] = sup_idx[b*LPAD + min(tj*GTILE + (tid - 64), nsc-1)];

    float acc[4][4];
    #pragma unroll
    for(int a = 0; a < 4; a++)
        #pragma unroll
        for(int c = 0; c < 4; c++) acc[a][c] = 0.f;

    for(int k0 = 0; k0 < DDIM; k0 += 32){
        __syncthreads();                       // Sb free (covers ia/ib at k0=0)
        #pragma unroll
        for(int t = 0; t < 2; t++){
            int f   = tid + t*256;
            int row = f >> 3, c4 = f & 7;
            float4 xa = *(const float4*)(X + (size_t)ia[row]*DDIM + k0 + 4*c4);
            float4 xb = *(const float4*)(X + (size_t)ib[row]*DDIM + k0 + 4*c4);
            Ast[(4*c4+0)*68 + row] = xa.x;
            Ast[(4*c4+1)*68 + row] = xa.y;
            Ast[(4*c4+2)*68 + row] = xa.z;
            Ast[(4*c4+3)*68 + row] = xa.w;
            Bst[(4*c4+0)*68 + row] = xb.x;
            Bst[(4*c4+1)*68 + row] = xb.y;
            Bst[(4*c4+2)*68 + row] = xb.z;
            Bst[(4*c4+3)*68 + row] = xb.w;
        }
        __syncthreads();
        #pragma unroll 8
        for(int k = 0; k < 32; k++){
            float4 af = *(const float4*)&Ast[k*68 + 4*ty];
            float4 bf = *(const float4*)&Bst[k*68 + 4*tx];
            acc[0][0] += af.x*bf.x; acc[0][1] += af.x*bf.y; acc[0][2] += af.x*bf.z; acc[0][3] += af.x*bf.w;
            acc[1][0] += af.y*bf.x; acc[1][1] += af.y*bf.y; acc[1][2] += af.y*bf.z; acc[1][3] += af.y*bf.w;
            acc[2][0] += af.z*bf.x; acc[2][1] += af.z*bf.y; acc[2][2] += af.z*bf.z; acc[2][3] += af.z*bf.w;
            acc[3][0] += af.w*bf.x; acc[3][1] += af.w*bf.y; acc[3][2] += af.w*bf.z; acc[3][3] += af.w*bf.w;
        }
    }

    // direct block (ti,tj): coalesced float4 rows, zero-masked padding
    #pragma unroll
    for(int a = 0; a < 4; a++){
        int i  = ti*GTILE + 4*ty + a;
        int j0 = tj*GTILE + 4*tx;
        float4 v;
        v.x = (i < nsc && j0+0 < nsc) ? acc[a][0] : 0.f;
        v.y = (i < nsc && j0+1 < nsc) ? acc[a][1] : 0.f;
        v.z = (i < nsc && j0+2 < nsc) ? acc[a][2] : 0.f;
        v.w = (i < nsc && j0+3 < nsc) ? acc[a][3] : 0.f;
        *(float4*)&G[(size_t)i*NS_CAP + j0] = v;
    }
    if(ti != tj){
        __syncthreads();                       // done with Ast/Bst
        #pragma unroll
        for(int a = 0; a < 4; a++)
            #pragma unroll
            for(int c = 0; c < 4; c++){
                int i = ti*GTILE + 4*ty + a;
                int j = tj*GTILE + 4*tx + c;
                Sb[(4*tx + c)*68 + 4*ty + a] = (i < nsc && j < nsc) ? acc[a][c] : 0.f;
            }
        __syncthreads();
        #pragma unroll
        for(int t = 0; t < 4; t++){
            int f = tid + t*256; int rr = f >> 4; int c4 = f & 15;
            float4 w = *(const float4*)&Sb[rr*68 + 4*c4];
            *(float4*)&G[(size_t)(tj*GTILE + rr)*NS_CAP + ti*GTILE + 4*c4] = w;
        }
    }
}

// ---------------------------------------------------------------------------
// Kernel 3: coefficient-space CG + reconstruction of v = M^-1 1.
// All iterates live in span{raw support rows}; one ns x ns Gram matvec/iter.
// Inner products are exact D-space ones via maintained t = G0 c vectors.
// One workgroup (512 threads) per (episode, class) system.
// ---------------------------------------------------------------------------
__global__ __launch_bounds__(512) void k_cgc(
        const float* __restrict__ X, const float* __restrict__ G0,
        const int* __restrict__ sup_idx, const int* __restrict__ sup_lab,
        const int* __restrict__ counts, const float* __restrict__ row_sums,
        float* __restrict__ vout)
{
    const int sys  = blockIdx.x;
    const int b    = sys >> 1;
    const int cls  = sys & 1;
    const int tid  = threadIdx.x;
    const int lane = tid & 63;
    const int wave = tid >> 6;

    __shared__ __align__(16) float u[NS_CAP];
    __shared__ float tq[NS_CAP];
    __shared__ float red1s[8];
    __shared__ float red2s[8][2];

    const int ns   = counts[b*4 + 0];
    const int nsc  = min(ns, NS_CAP);
    const int ncls = cls ? counts[b*4 + 2] : counts[b*4 + 3];
    const float c_task = 0.9f / (float)(ns - 1);
    const float c_cls  = 0.1f / (float)(ncls - 1);
    const float inv_ns = 1.f / (float)ns;
    const float inv_nc = 1.f / (float)ncls;
    const float* G = G0 + (size_t)b * NS_CAP * NS_CAP;

    const bool own = tid < nsc;
    float mfl = 0.f, sraw = 0.f;
    if(own){
        mfl  = (sup_lab[b*LPAD + tid] == cls) ? 1.f : 0.f;
        sraw = row_sums[b*LPAD + tid];
    }

    auto reduce1 = [&](float v) -> float {
        #pragma unroll
        for(int off = 32; off; off >>= 1) v += __shfl_xor(v, off);
        __syncthreads();
        if(lane == 0) red1s[wave] = v;
        __syncthreads();
        float s = 0.f;
        #pragma unroll
        for(int w = 0; w < 8; w++) s += red1s[w];
        return s;
    };
    auto reduce2 = [&](float a, float c, float& oa, float& oc){
        #pragma unroll
        for(int off = 32; off; off >>= 1){ a += __shfl_xor(a, off); c += __shfl_xor(c, off); }
        __syncthreads();
        if(lane == 0){ red2s[wave][0] = a; red2s[wave][1] = c; }
        __syncthreads();
        oa = 0.f; oc = 0.f;
        #pragma unroll
        for(int w = 0; w < 8; w++){ oa += red2s[w][0]; oc += red2s[w][1]; }
    };
    auto matvec = [&](){                       // tq[0..nsc) = G0 * u
        const int nf4 = (nsc + 3) >> 2;
        const float4* uf4 = (const float4*)u;
        for(int r = wave; r < nsc; r += 16){
            int r2  = r + 8;
            int r2c = (r2 < nsc) ? r2 : r;
            const float4* row0 = (const float4*)(G + (size_t)r   * NS_CAP);
            const float4* row1 = (const float4*)(G + (size_t)r2c * NS_CAP);
            float s0 = 0.f, s1 = 0.f;
            for(int c = lane; c < nf4; c += 64){
                float4 uu = uf4[c];
                float4 g0 = row0[c];
                float4 g1 = row1[c];
                s0 += g0.x*uu.x + g0.y*uu.y + g0.z*uu.z + g0.w*uu.w;
                s1 += g1.x*uu.x + g1.y*uu.y + g1.z*uu.z + g1.w*uu.w;
            }
            #pragma unroll
            for(int off = 32; off; off >>= 1){ s0 += __shfl_xor(s0, off); s1 += __shfl_xor(s1, off); }
            if(lane == 0){ tq[r] = s0; if(r2 < nsc) tq[r2] = s1; }
        }
    };

    // r0 = 1 - M(10*1) = -10 * A * 1  (t for p=1_D is the row-sum vector)
    float A0, A1;
    reduce2(sraw, mfl * sraw, A0, A1);
    A0 *= inv_ns; A1 *= inv_nc;
    float cr = own ? -10.f * (c_task*(sraw - A0) + mfl*c_cls*(sraw - A1)) : 0.f;
    if(tid < NS_CAP) u[tid] = cr;
    __syncthreads();
    matvec();
    __syncthreads();
    float tr  = own ? tq[tid] : 0.f;
    float cp  = cr, tpv = tr, cx = 0.f;
    float rr  = reduce1(cr * tr);

    for(int it = 0; it < CG_ITERS; ++it){
        reduce2(tpv, mfl * tpv, A0, A1);
        A0 *= inv_ns; A1 *= inv_nc;
        float ui = own ? (c_task*(tpv - A0) + mfl*c_cls*(tpv - A1)) : 0.f;
        float qc = 0.1f*cp + ui;               // c_q = 0.1 c_p + u
        if(tid < NS_CAP) u[tid] = ui;
        float pq = reduce1(tpv * qc);          // (p,q) = t_p^T c_q; barrier publishes u
        matvec();                              // G0 * u
        __syncthreads();
        float tqf = 0.1f*tpv + (own ? tq[tid] : 0.f);   // t_q = 0.1 t_p + G0 u
        float alpha = rr / pq;
        cx += alpha * cp;
        cr -= alpha * qc;
        tr -= alpha * tqf;
        float rrn = reduce1(cr * tr);
        float beta = rrn / rr;
        rr = rrn;
        cp  = cr + beta * cp;
        tpv = tr + beta * tpv;
        if(rr < 1e-26f) break;                 // uniform across block
    }

    // v = 10*1 + Xs^T c_x
    __syncthreads();
    if(tid < NS_CAP) u[tid] = own ? cx : 0.f;
    __syncthreads();
    float v = 10.f;
    int s = 0;
    for(; s + 4 <= nsc; s += 4){
        int n0 = sup_idx[b*LPAD + s + 0];
        int n1 = sup_idx[b*LPAD + s + 1];
        int n2 = sup_idx[b*LPAD + s + 2];
        int n3 = sup_idx[b*LPAD + s + 3];
        float x0 = X[(size_t)n0*DDIM + tid];
        float x1 = X[(size_t)n1*DDIM + tid];
        float x2 = X[(size_t)n2*DDIM + tid];
        float x3 = X[(size_t)n3*DDIM + tid];
        v += u[s]*x0 + u[s+1]*x1 + u[s+2]*x2 + u[s+3]*x3;
    }
    for(; s < nsc; s++) v += u[s] * X[(size_t)sup_idx[b*LPAD + s]*DDIM + tid];
    vout[(size_t)sys * DDIM + tid] = v;
}

// ---------------------------------------------------------------------------
// Fallback kernel (old D-space CG) if workspace is too small for G0.
// ---------------------------------------------------------------------------
__global__ __launch_bounds__(512) void k_cg(
        const float* __restrict__ X,
        const int* __restrict__ sup_idx, const int* __restrict__ sup_lab,
        const int* __restrict__ counts,
        const float* __restrict__ task_mean, const float* __restrict__ pos_mean,
        const float* __restrict__ neg_mean,
        float* __restrict__ vout)
{
    const int sys  = blockIdx.x;
    const int b    = sys >> 1;
    const int cls  = sys & 1;
    const int tid  = threadIdx.x;
    const int lane = tid & 63;
    const int wave = tid >> 6;
    const int d    = tid;

    __shared__ float xs[CHUNK][DDIM];
    __shared__ float p_lds[DDIM];
    __shared__ float w_lds[CHUNK];
    __shared__ int   lab_lds[CHUNK];
    __shared__ int   idx_lds[CHUNK];
    __shared__ float red1[8];
    __shared__ float red2[8][2];

    const int ns   = counts[b*4 + 0];
    const int ncls = cls ? counts[b*4 + 2] : counts[b*4 + 3];
    const float c_task = 0.9f / (float)(ns - 1);
    const float c_cls  = 0.1f / (float)(ncls - 1);
    const float mu_d    = task_mean[b*DDIM + d];
    const float mucls_d = cls ? pos_mean[b*DDIM + d] : neg_mean[b*DDIM + d];

    auto blockReduce = [&](float v) -> float {
        #pragma unroll
        for(int off = 32; off; off >>= 1) v += __shfl_xor(v, off);
        __syncthreads();
        if(lane == 0) red1[wave] = v;
        __syncthreads();
        float s = 0.f;
        #pragma unroll
        for(int w = 0; w < 8; w++) s += red1[w];
        return s;
    };
    auto matvec = [&](float pd_reg) -> float {
        float part0 = mu_d * pd_reg, part1 = mucls_d * pd_reg;
        #pragma unroll
        for(int off = 32; off; off >>= 1){
            part0 += __shfl_xor(part0, off);
            part1 += __shfl_xor(part1, off);
        }
        __syncthreads();
        if(lane == 0){ red2[wave][0] = part0; red2[wave][1] = part1; }
        __syncthreads();
        float a0 = 0.f, a1 = 0.f;
        #pragma unroll
        for(int w = 0; w < 8; w++){ a0 += red2[w][0]; a1 += red2[w][1]; }
        float preg[8];
        #pragma unroll
        for(int k = 0; k < 8; k++) preg[k] = p_lds[lane + 64*k];
        float q = 0.1f * pd_reg;
        for(int cs = 0; cs < ns; cs += CHUNK){
            int nrows = min(CHUNK, ns - cs);
            __syncthreads();
            if(tid < nrows){
                idx_lds[tid] = sup_idx[b * LPAD + cs + tid];
                lab_lds[tid] = sup_lab[b * LPAD + cs + tid];
            }
            __syncthreads();
            for(int f = tid; f < nrows * 128; f += 512){
                int r  = f >> 7;
                int c4 = f & 127;
                const float4* src = (const float4*)(X + (size_t)idx_lds[r] * DDIM);
                ((float4*)&xs[r][0])[c4] = src[c4];
            }
            __syncthreads();
            for(int r = wave; r < nrows; r += 8){
                float t = 0.f;
                #pragma unroll
                for(int k = 0; k < 8; k++) t += xs[r][lane + 64*k] * preg[k];
                #pragma unroll
                for(int off = 32; off; off >>= 1) t += __shfl_xor(t, off);
                if(lane == 0){
                    int lm = (lab_lds[r] == cls) ? 1 : 0;
                    w_lds[r] = c_task * (t - a0) + (lm ? c_cls * (t - a1) : 0.f);
                }
            }
            __syncthreads();
            for(int r = 0; r < nrows; r++) q += w_lds[r] * xs[r][d];
        }
        return q;
    };

    float xv = 10.0f;
    float pd = 10.0f;
    p_lds[d] = pd;
    __syncthreads();
    float qd = matvec(pd);
    float rd = 1.0f - qd;
    pd = rd;
    float rr = blockReduce(rd * rd);
    __syncthreads();
    p_lds[d] = pd;
    __syncthreads();

    for(int it = 0; it < CG_ITERS_FB; it++){
        if(rr < 1e-30f) break;
        qd = matvec(pd);
        float pq = blockReduce(pd * qd);
        float alpha = rr / pq;
        xv += alpha * pd;
        rd -= alpha * qd;
        float rr_new = blockReduce(rd * rd);
        float beta = rr_new / rr;
        rr = rr_new;
        pd = rd + beta * pd;
        __syncthreads();
        p_lds[d] = pd;
        __syncthreads();
    }
    vout[(size_t)(b*2 + cls) * DDIM + d] = xv;
}

// ---------------------------------------------------------------------------
// Kernel 4: per-query output (unchanged).
// ---------------------------------------------------------------------------
__global__ __launch_bounds__(256) void k_out(
        const float* __restrict__ X,
        const int* __restrict__ qry_idx, const int* __restrict__ counts,
        const float* __restrict__ pos_mean, const float* __restrict__ neg_mean,
        const float* __restrict__ vsol, const float* __restrict__ log_scale,
        float* __restrict__ out)
{
    const int b    = blockIdx.x;
    const int tid  = threadIdx.x;
    const int lane = tid & 63;
    const int wave = tid >> 6;

    __shared__ float vpos[DDIM], vneg[DDIM];
    __shared__ float red4[4][4];
    __shared__ float sc[4];

    const int nq  = counts[b*4 + 1];
    const int nqc = min(nq, LPAD);
    const float scale = expf(log_scale[0]);

    float pm0 = pos_mean[b*DDIM + tid], pm1 = pos_mean[b*DDIM + tid + 256];
    float nm0 = neg_mean[b*DDIM + tid], nm1 = neg_mean[b*DDIM + tid + 256];
    float vp0 = vsol[(size_t)(b*2 + 1) * DDIM + tid];
    float vp1 = vsol[(size_t)(b*2 + 1) * DDIM + tid + 256];
    float vn0 = vsol[(size_t)(b*2 + 0) * DDIM + tid];
    float vn1 = vsol[(size_t)(b*2 + 0) * DDIM + tid + 256];
    vpos[tid] = vp0; vpos[tid + 256] = vp1;
    vneg[tid] = vn0; vneg[tid + 256] = vn1;

    float smp = pm0 + pm1;
    float smn = nm0 + nm1;
    float mvp = pm0 * vp0 + pm1 * vp1;
    float mvn = nm0 * vn0 + nm1 * vn1;
    #pragma unroll
    for(int off = 32; off; off >>= 1){
        smp += __shfl_xor(smp, off);
        smn += __shfl_xor(smn, off);
        mvp += __shfl_xor(mvp, off);
        mvn += __shfl_xor(mvn, off);
    }
    if(lane == 0){
        red4[wave][0] = smp; red4[wave][1] = smn;
        red4[wave][2] = mvp; red4[wave][3] = mvn;
    }
    __syncthreads();
    if(tid < 4) sc[tid] = red4[0][tid] + red4[1][tid] + red4[2][tid] + red4[3][tid];
    __syncthreads();

    for(int r = wave; r < nqc; r += 4){
        int n = qry_idx[b * LPAD + r];
        float tp = 0.f, tn = 0.f, sx = 0.f;
        #pragma unroll
        for(int k = 0; k < 8; k++){
            float x = X[(size_t)n * DDIM + lane + 64*k];
            tp += x * vpos[lane + 64*k];
            tn += x * vneg[lane + 64*k];
            sx += x;
        }
        #pragma unroll
        for(int off = 32; off; off >>= 1){
            tp += __shfl_xor(tp, off);
            tn += __shfl_xor(tn, off);
            sx += __shfl_xor(sx, off);
        }
        if(lane == 0){
            float mp = (tp - sc[2]) * (sx - sc[0]);
            float mn = (tn - sc[3]) * (sx - sc[1]);
            ((float2*)out)[(size_t)b * LPAD + r] = make_float2(mn * scale, mp * scale);
        }
    }
    for(int r = nqc + tid; r < LPAD; r += 256)
        ((float2*)out)[(size_t)b * LPAD + r] = make_float2(0.f, 0.f);
}

// ---------------------------------------------------------------------------
extern "C" void kernel_launch(void* const* d_in, const int* in_sizes, int n_in,
                              void* d_out, int out_size, void* d_ws, size_t ws_size,
                              hipStream_t stream)
{
    const float* X         = (const float*)d_in[0];
    const float* log_scale = (const float*)d_in[1];
    const int*   labels    = (const int*)d_in[2];
    const int*   is_query  = (const int*)d_in[3];
    const int*   bidx      = (const int*)d_in[4];
    const int N = in_sizes[2];

    char* ws = (char*)d_ws;
    auto alloc = [&](size_t bytes) -> char* {
        char* p = ws;
        ws += (bytes + 255) & ~(size_t)255;
        return p;
    };
    int*   sup_idx   = (int*)  alloc((size_t)EPISODES * LPAD * sizeof(int));
    int*   qry_idx   = (int*)  alloc((size_t)EPISODES * LPAD * sizeof(int));
    int*   sup_lab   = (int*)  alloc((size_t)EPISODES * LPAD * sizeof(int));
    int*   counts    = (int*)  alloc((size_t)EPISODES * 4 * sizeof(int));
    float* task_mean = (float*)alloc((size_t)EPISODES * DDIM * sizeof(float));
    float* pos_mean  = (float*)alloc((size_t)EPISODES * DDIM * sizeof(float));
    float* neg_mean  = (float*)alloc((size_t)EPISODES * DDIM * sizeof(float));
    float* vsol      = (float*)alloc((size_t)EPISODES * 2 * DDIM * sizeof(float));
    float* row_sums  = (float*)alloc((size_t)EPISODES * LPAD * sizeof(float));
    float* G0        = (float*)alloc((size_t)EPISODES * NS_CAP * NS_CAP * sizeof(float));
    const size_t used = (size_t)(ws - (char*)d_ws);
    const bool fits = used <= ws_size;         // constant per process -> graph-safe

    k_gather<<<EPISODES, 256, 0, stream>>>(labels, is_query, bidx, X, N,
                                           sup_idx, qry_idx, sup_lab, counts,
                                           task_mean, pos_mean, neg_mean, row_sums);
    if(fits){
        k_gram<<<EPISODES * NPAIRS, 256, 0, stream>>>(X, sup_idx, counts, G0);
        k_cgc<<<EPISODES * 2, 512, 0, stream>>>(X, G0, sup_idx, sup_lab, counts,
                                                row_sums, vsol);
    } else {
        k_cg<<<EPISODES * 2, 512, 0, stream>>>(X, sup_idx, sup_lab, counts,
                                               task_mean, pos_mean, neg_mean, vsol);
    }
    k_out<<<EPISODES, 256, 0, stream>>>(X, qry_idx, counts, pos_mean, neg_mean,
                                        vsol, log_scale, (float*)d_out);
}